// Round 17
// baseline (182.892 us; speedup 1.0000x reference)
//
#include <hip/hip_runtime.h>
#include <hip/hip_fp16.h>
#include <hip/hip_cooperative_groups.h>

namespace cg = cooperative_groups;

typedef __fp16 h2 __attribute__((ext_vector_type(2)));
typedef __fp16 v4h __attribute__((ext_vector_type(4)));
typedef float f32x4 __attribute__((ext_vector_type(4)));

__device__ inline float wave_sum(float v) {
#pragma unroll
    for (int off = 32; off > 0; off >>= 1) v += __shfl_down(v, off, 64);
    return v;
}

__device__ inline v4h relu_pack(f32x4 d) {
    h2 lo = __builtin_amdgcn_cvt_pkrtz(d[0], d[1]);
    h2 hi = __builtin_amdgcn_cvt_pkrtz(d[2], d[3]);
    h2 z = {(__fp16)0, (__fp16)0};
    lo = __builtin_elementwise_max(lo, z);
    hi = __builtin_elementwise_max(hi, z);
    v4h r = {lo.x, lo.y, hi.x, hi.y};
    return r;
}

// ---- per-c-pair MFMA fragments (R13-verified mapping) ----
struct Frags { v4h A1, A2, A3; f32x4 C1, C2, C3; };

__device__ inline Frags make_frags(const __fp16* ph, const float* smemf, int c0,
                                   int csel, int o, int dup, int crow,
                                   bool ok1, bool okBD) {
    Frags f;
    int cbA = (c0 + csel) * 160;
    int cbB = (c0 + crow) * 160;
    v4h z = {(__fp16)0, (__fp16)0, (__fp16)0, (__fp16)0};
    v4h a1 = *(const v4h*)(ph + cbA + o * 8 + dup * 4);
    v4h a2 = *(const v4h*)(ph + cbA + 64 + o * 8 + dup * 4);
    v4h a3 = *(const v4h*)(ph + cbA + 128 + dup * 4);
    f.A1 = ok1 ? a1 : z;
    f.A2 = okBD ? a2 : z;
    f.A3 = (okBD && o == 0) ? a3 : z;
    v4h b1 = *(const v4h*)(ph + cbB + 136 + dup * 4);
    v4h b2 = *(const v4h*)(ph + cbB + 144 + dup * 4);
    f.C1 = f32x4{(float)b1.x, (float)b1.y, (float)b1.z, (float)b1.w};
    f.C2 = f32x4{(float)b2.x, (float)b2.y, (float)b2.z, (float)b2.w};
    f.C3 = f32x4{0.f, 0.f, 0.f, 0.f};
    if (dup == 0) f.C3[0] = smemf[(c0 + crow) * 80 + 76];
    return f;
}

// ================= Cooperative mega kernel: 256 blocks x 512 =================
// Phase A: 608 tasks (512 feat-stat chunks, 64 dec4 groups, 32 E rows) looped
//          over 256 blocks.  grid.sync
// Phase B: fc (blocks 0..3, pair-split) -> packed f16 params in ws.  grid.sync
// Phase C: per block one (b, 1024-px tile): head + MFMA MLP (R13 mapping).
__global__ __launch_bounds__(512) void mega(
    const float* __restrict__ feat, const float* __restrict__ dec4,
    const float* __restrict__ gn_pre_gamma, const float* __restrict__ gn_pre_beta,
    const float* __restrict__ W_pre, const float* __restrict__ b_pre,
    const float* __restrict__ gn_gap_gamma, const float* __restrict__ gn_gap_beta,
    const float* __restrict__ W_gap, const float* __restrict__ b_gap,
    const float* __restrict__ emb, const float* __restrict__ W_ctrl,
    const float* __restrict__ b_ctrl, float* __restrict__ out,
    float* __restrict__ partials, float* __restrict__ g_buf,
    float* __restrict__ E_ws, unsigned char* __restrict__ pk) {
    cg::grid_group grid = cg::this_grid();
    __shared__ __align__(16) float smem[6816];   // 27264 B
    const int k = blockIdx.x;
    const int tid = threadIdx.x;
    const int w = tid >> 6, lane = tid & 63;
    float* ls = smem + 6656;
    float* lq = smem + 6664;
    float* bc = smem + 6672;

    // ---------------- Phase A ----------------
    for (int t = k; t < 608; t += 256) {
        if (t < 512) {
            int grp = t >> 3, chunk = t & 7;
            const float4* base = (const float4*)(feat + (size_t)grp * 262144 + (size_t)chunk * 32768);
            float sa = 0.f, qa = 0.f, sb = 0.f, qb = 0.f;
#pragma unroll 4
            for (int i = 0; i < 8; ++i) {
                float4 v = base[i * 512 + tid];
                float4 u = base[(i + 8) * 512 + tid];
                sa += v.x + v.y + v.z + v.w;
                qa += v.x * v.x + v.y * v.y + v.z * v.z + v.w * v.w;
                sb += u.x + u.y + u.z + u.w;
                qb += u.x * u.x + u.y * u.y + u.z * u.z + u.w * u.w;
            }
            float s = wave_sum(sa + sb);
            float q = wave_sum(qa + qb);
            if (lane == 0) { ls[w] = s; lq[w] = q; }
            __syncthreads();
            if (tid == 0) {
                float S = 0.f, Q = 0.f;
#pragma unroll
                for (int i = 0; i < 8; ++i) { S += ls[i]; Q += lq[i]; }
                partials[t * 2 + 0] = S;
                partials[t * 2 + 1] = Q;
            }
        } else if (t < 576) {
            int idx = t - 512;            // b*16+gi
            int b = idx >> 4, gi = idx & 15;
            const float* base = dec4 + (size_t)idx * 8192;
            int ch = tid >> 4, sub = tid & 15;
            const float4* r = (const float4*)(base + ch * 256 + sub * 16);
            float v[16];
            float s = 0.f, q = 0.f;
#pragma unroll
            for (int i = 0; i < 4; ++i) {
                float4 a = r[i];
                v[i * 4 + 0] = a.x; v[i * 4 + 1] = a.y; v[i * 4 + 2] = a.z; v[i * 4 + 3] = a.w;
                s += a.x + a.y + a.z + a.w;
                q += a.x * a.x + a.y * a.y + a.z * a.z + a.w * a.w;
            }
            s = wave_sum(s); q = wave_sum(q);
            if (lane == 0) { ls[w] = s; lq[w] = q; }
            __syncthreads();
            if (tid == 0) {
                float S = 0.f, Q = 0.f;
#pragma unroll
                for (int i = 0; i < 8; ++i) { S += ls[i]; Q += lq[i]; }
                const float inv = 1.f / 8192.f;
                float mu = S * inv;
                float var = Q * inv - mu * mu;
                bc[0] = mu;
                bc[1] = rsqrtf(var + 1e-5f);
            }
            __syncthreads();
            float mu = bc[0], rs = bc[1];
            int c = gi * 32 + ch;
            float sc = rs * gn_gap_gamma[c];
            float sh = gn_gap_beta[c] - mu * sc;
            float acc = 0.f;
#pragma unroll
            for (int i = 0; i < 16; ++i) acc += fmaxf(v[i] * sc + sh, 0.f);
#pragma unroll
            for (int m = 1; m < 16; m <<= 1) acc += __shfl_xor(acc, m, 64);
            if (sub == 0) g_buf[b * 512 + c] = acc * (1.f / 256.f);
        } else {
            int c = t - 576;
            if (tid < 256) smem[tid] = emb[c * 256 + tid];
            __syncthreads();
            if (tid < 153) {
                const float4* w4 = (const float4*)(W_ctrl + tid * 512 + 256);
                const float4* e4 = (const float4*)smem;
                float acc = 0.f;
#pragma unroll 8
                for (int kk = 0; kk < 64; ++kk) {
                    float4 a = w4[kk], e = e4[kk];
                    acc += a.x * e.x + a.y * e.y + a.z * e.z + a.w * e.w;
                }
                E_ws[c * 153 + tid] = acc;
            }
        }
        __syncthreads();
    }

    grid.sync();

    // ---------------- Phase B: fc (blocks 0..3) ----------------
    if (k < 4) {
        int b = k;
        float* gs = smem;            // 512
        float* xf = smem + 512;      // 256
        float* F  = smem + 768;      // 160
        gs[tid] = g_buf[b * 512 + tid];
        __syncthreads();
        {
            int o = tid >> 1, h = tid & 1;
            const float4* wrow = (const float4*)(W_gap + o * 512 + h * 256);
            const float4* gg = (const float4*)(gs + h * 256);
            float acc = 0.f;
#pragma unroll 8
            for (int kk = 0; kk < 64; ++kk) {
                float4 a = wrow[kk], g = gg[kk];
                acc += a.x * g.x + a.y * g.y + a.z * g.z + a.w * g.w;
            }
            acc += __shfl_xor(acc, 1, 64);
            if (h == 0) xf[o] = acc + b_gap[o];
        }
        __syncthreads();
        if (tid < 306) {
            int o = tid >> 1, h = tid & 1;
            const float4* wrow = (const float4*)(W_ctrl + o * 512 + h * 128);
            const float4* xx = (const float4*)(xf + h * 128);
            float acc = 0.f;
#pragma unroll 8
            for (int kk = 0; kk < 32; ++kk) {
                float4 a = wrow[kk], x = xx[kk];
                acc += a.x * x.x + a.y * x.y + a.z * x.z + a.w * x.w;
            }
            acc += __shfl_xor(acc, 1, 64);
            if (h == 0) F[o] = acc + b_ctrl[o];
        }
        __syncthreads();
        unsigned char* dst = pk + (size_t)b * 10240;
        for (int i = tid; i < 5120; i += 512) {
            int c = i / 160, oo = i - c * 160;
            if (oo < 152) {
                ((__fp16*)(dst + c * 320))[oo] = (__fp16)(F[oo] + E_ws[c * 153 + oo]);
            } else if (oo == 152) {
                *(float*)(dst + c * 320 + 304) = F[152] + E_ws[c * 153 + 152];
            }
        }
    }

    grid.sync();

    // ---------------- Phase C: head + MFMA MLP, 1024-px tile ----------------
    {
        int b = k >> 6;
        int P0 = (k & 63) << 10;
        float4* pp   = (float4*)smem;               // [0,2560)f
        float4* hi_l = (float4*)(smem + 2560);      // [2560,6656)f : 1024 px
        float2* sch  = (float2*)(smem + 6656);      // 64 x (sc, sh)
        float* mus = smem + 6784;
        float* rss = smem + 6800;

        const float4* src = (const float4*)(pk + (size_t)b * 10240);
        for (int i = tid; i < 640; i += 512) pp[i] = src[i];

        if (tid < 16) {
            float s = 0.f, q = 0.f;
#pragma unroll
            for (int cc = 0; cc < 8; ++cc) {
                int idx = ((b * 16 + tid) * 8 + cc) * 2;
                s += partials[idx]; q += partials[idx + 1];
            }
            const float inv = 1.f / 262144.f;
            float mu = s * inv;
            float var = q * inv - mu * mu;
            mus[tid] = mu; rss[tid] = rsqrtf(var + 1e-5f);
        }
        __syncthreads();
        if (tid < 64) {
            float mu = mus[tid >> 2], rs = rss[tid >> 2];
            float sg = rs * gn_pre_gamma[tid];
            sch[tid] = make_float2(sg, gn_pre_beta[tid] - mu * sg);
        }
        __syncthreads();

        // head: 2 px per thread
#pragma unroll 1
        for (int hh = 0; hh < 2; ++hh) {
            int px = (hh << 9) + tid;
            float hi[8];
#pragma unroll
            for (int o2 = 0; o2 < 8; ++o2) hi[o2] = b_pre[o2];
            const float* fb = feat + ((size_t)b << 22) + P0 + px;
#pragma unroll
            for (int ch = 0; ch < 64; ++ch) {
                float v = fb[(size_t)ch << 16];
                float2 ss = sch[ch];
                float pre = fmaxf(v * ss.x + ss.y, 0.f);
#pragma unroll
                for (int o2 = 0; o2 < 8; ++o2) hi[o2] += W_pre[o2 * 64 + ch] * pre;
            }
            float4 hq;
            hq.x = __builtin_bit_cast(float, __builtin_amdgcn_cvt_pkrtz(hi[0], hi[1]));
            hq.y = __builtin_bit_cast(float, __builtin_amdgcn_cvt_pkrtz(hi[2], hi[3]));
            hq.z = __builtin_bit_cast(float, __builtin_amdgcn_cvt_pkrtz(hi[4], hi[5]));
            hq.w = __builtin_bit_cast(float, __builtin_amdgcn_cvt_pkrtz(hi[6], hi[7]));
            hi_l[px] = hq;
        }
        __syncthreads();

        const __fp16* ph = (const __fp16*)smem;
        int m = lane & 15;
        int kg = lane >> 4;
        int csel = m >> 3;
        int o = m & 7;
        int dup = kg & 1;
        int crow = kg >> 1;
        bool ok1 = (kg < 2);
        bool okBD = (crow == csel);
        bool act = (dup == 0);

        int cA = w << 2;
        int cB = cA + 2;
        Frags fa = make_frags(ph, smem, cA, csel, o, dup, crow, ok1, okBD);
        Frags fb2 = make_frags(ph, smem, cB, csel, o, dup, crow, ok1, okBD);

        float* ob = out + ((size_t)b << 21) + P0;
        float* cpA = ob + ((size_t)(cA + crow) << 16) + m;
        float* cpB = ob + ((size_t)(cB + crow) << 16) + m;
        const __fp16* hp = ph + 5120 + m * 8 + dup * 4;

#pragma unroll 4
        for (int g = 0; g < 64; ++g) {
            v4h B1 = *(const v4h*)(hp + g * 128);
            f32x4 d1a = __builtin_amdgcn_mfma_f32_16x16x16f16(fa.A1, B1, fa.C1, 0, 0, 0);
            f32x4 d1b = __builtin_amdgcn_mfma_f32_16x16x16f16(fb2.A1, B1, fb2.C1, 0, 0, 0);
            v4h p2a = relu_pack(d1a);
            v4h p2b = relu_pack(d1b);
            f32x4 d2a = __builtin_amdgcn_mfma_f32_16x16x16f16(fa.A2, p2a, fa.C2, 0, 0, 0);
            f32x4 d2b = __builtin_amdgcn_mfma_f32_16x16x16f16(fb2.A2, p2b, fb2.C2, 0, 0, 0);
            v4h p3a = relu_pack(d2a);
            v4h p3b = relu_pack(d2b);
            f32x4 d3a = __builtin_amdgcn_mfma_f32_16x16x16f16(fa.A3, p3a, fa.C3, 0, 0, 0);
            f32x4 d3b = __builtin_amdgcn_mfma_f32_16x16x16f16(fb2.A3, p3b, fb2.C3, 0, 0, 0);
            if (act) {
                cpA[g * 16] = d3a[0];
                cpB[g * 16] = d3b[0];
            }
        }
    }
}

// ================= Fallback path: R13-exact 3 kernels =================
__global__ __launch_bounds__(256) void prep(
    const float* __restrict__ feat, const float* __restrict__ dec4,
    const float* __restrict__ gn_gap_gamma, const float* __restrict__ gn_gap_beta,
    const float* __restrict__ emb, const float* __restrict__ W_ctrl,
    float* __restrict__ partials, float* __restrict__ g_buf,
    float* __restrict__ E_ws) {
    int blk = blockIdx.x;
    int tid = threadIdx.x;
    int wid = tid >> 6, lane = tid & 63;
    if (blk < 512) {
        int grp = blk >> 3;
        int chunk = blk & 7;
        const float4* base = (const float4*)(feat + (size_t)grp * 262144 + (size_t)chunk * 32768);
        float sa = 0.f, qa = 0.f, sb = 0.f, qb = 0.f;
#pragma unroll 8
        for (int i = 0; i < 16; ++i) {
            float4 v = base[i * 256 + tid];
            float4 u = base[(i + 16) * 256 + tid];
            sa += v.x + v.y + v.z + v.w;
            qa += v.x * v.x + v.y * v.y + v.z * v.z + v.w * v.w;
            sb += u.x + u.y + u.z + u.w;
            qb += u.x * u.x + u.y * u.y + u.z * u.z + u.w * u.w;
        }
        __shared__ float ls[4], lq[4];
        float s = wave_sum(sa + sb);
        float q = wave_sum(qa + qb);
        if (lane == 0) { ls[wid] = s; lq[wid] = q; }
        __syncthreads();
        if (tid == 0) {
            partials[blk * 2 + 0] = ls[0] + ls[1] + ls[2] + ls[3];
            partials[blk * 2 + 1] = lq[0] + lq[1] + lq[2] + lq[3];
        }
    } else if (blk < 576) {
        int idx = blk - 512;
        int b = idx >> 4, gi = idx & 15;
        const float* base = dec4 + (size_t)idx * 8192;
        int ch = tid >> 3, sub = tid & 7;
        const float4* r = (const float4*)(base + ch * 256 + sub * 32);
        float v[32];
        float s = 0.f, q = 0.f;
#pragma unroll
        for (int i = 0; i < 8; ++i) {
            float4 a = r[i];
            v[i * 4 + 0] = a.x; v[i * 4 + 1] = a.y; v[i * 4 + 2] = a.z; v[i * 4 + 3] = a.w;
            s += a.x + a.y + a.z + a.w;
            q += a.x * a.x + a.y * a.y + a.z * a.z + a.w * a.w;
        }
        __shared__ float ls[4], lq[4], bc[2];
        s = wave_sum(s); q = wave_sum(q);
        if (lane == 0) { ls[wid] = s; lq[wid] = q; }
        __syncthreads();
        if (tid == 0) {
            float S = ls[0] + ls[1] + ls[2] + ls[3];
            float Q = lq[0] + lq[1] + lq[2] + lq[3];
            const float inv = 1.f / 8192.f;
            float mu = S * inv;
            float var = Q * inv - mu * mu;
            bc[0] = mu;
            bc[1] = rsqrtf(var + 1e-5f);
        }
        __syncthreads();
        float mu = bc[0], rs = bc[1];
        int c = gi * 32 + ch;
        float sc = rs * gn_gap_gamma[c];
        float sh = gn_gap_beta[c] - mu * sc;
        float acc = 0.f;
#pragma unroll
        for (int i = 0; i < 32; ++i) acc += fmaxf(v[i] * sc + sh, 0.f);
#pragma unroll
        for (int m = 1; m < 8; m <<= 1) acc += __shfl_xor(acc, m, 64);
        if (sub == 0) g_buf[b * 512 + c] = acc * (1.f / 256.f);
    } else {
        int c = blk - 576;
        __shared__ float es[256];
        es[tid] = emb[c * 256 + tid];
        __syncthreads();
        if (tid < 153) {
            const float4* w4 = (const float4*)(W_ctrl + tid * 512 + 256);
            const float4* e4 = (const float4*)es;
            float acc = 0.f;
#pragma unroll 8
            for (int kk = 0; kk < 64; ++kk) {
                float4 a = w4[kk], e = e4[kk];
                acc += a.x * e.x + a.y * e.y + a.z * e.z + a.w * e.w;
            }
            E_ws[c * 153 + tid] = acc;
        }
    }
}

__global__ __launch_bounds__(256) void fc(
    const float* __restrict__ g_buf, const float* __restrict__ W_gap,
    const float* __restrict__ b_gap, const float* __restrict__ W_ctrl,
    const float* __restrict__ b_ctrl, const float* __restrict__ E_ws,
    unsigned char* __restrict__ pk) {
    int b = blockIdx.x, tid = threadIdx.x;
    __shared__ float gs[512];
    __shared__ float xf[256];
    __shared__ float F[160];
    gs[tid] = g_buf[b * 512 + tid];
    gs[tid + 256] = g_buf[b * 512 + 256 + tid];
    __syncthreads();
    {
        const float4* w = (const float4*)(W_gap + tid * 512);
        const float4* g4 = (const float4*)gs;
        float acc = b_gap[tid];
#pragma unroll 8
        for (int kk = 0; kk < 128; ++kk) {
            float4 wv = w[kk], gv = g4[kk];
            acc += wv.x * gv.x + wv.y * gv.y + wv.z * gv.z + wv.w * gv.w;
        }
        xf[tid] = acc;
    }
    __syncthreads();
    if (tid < 160) {
        float acc = 0.f;
        if (tid < 153) {
            const float4* w = (const float4*)(W_ctrl + tid * 512);
            const float4* x4 = (const float4*)xf;
#pragma unroll 8
            for (int kk = 0; kk < 64; ++kk) {
                float4 wv = w[kk], xv = x4[kk];
                acc += wv.x * xv.x + wv.y * xv.y + wv.z * xv.z + wv.w * xv.w;
            }
            acc += b_ctrl[tid];
        }
        F[tid] = acc;
    }
    __syncthreads();
    unsigned char* dst = pk + (size_t)b * 10240;
    for (int c = 0; c < 32; ++c) {
        if (tid < 152) {
            float v = F[tid] + E_ws[c * 153 + tid];
            ((__fp16*)(dst + c * 320))[tid] = (__fp16)v;
        } else if (tid == 152) {
            *(float*)(dst + c * 320 + 304) = F[152] + E_ws[c * 153 + 152];
        }
    }
}

__global__ __launch_bounds__(512, 4) void mainK(
    const float* __restrict__ feat, const float* __restrict__ partials,
    const float* __restrict__ gamma, const float* __restrict__ beta,
    const float* __restrict__ W_pre, const float* __restrict__ b_pre,
    const float4* __restrict__ pk, float* __restrict__ out) {
    int blk = blockIdx.x;
    int b = blk >> 7;
    int tid = threadIdx.x;
    int w = tid >> 6, lane = tid & 63;
    int P0 = (blk & 127) << 9;

    __shared__ __align__(16) float smem[4768];
    float4* pp   = (float4*)smem;
    float4* hi_l = (float4*)(smem + 2560);
    float2* sch  = (float2*)(smem + 4608);
    float* mus = smem + 4736;
    float* rss = smem + 4752;

    const float4* src = pk + (size_t)b * 640;
    for (int i = tid; i < 640; i += 512) pp[i] = src[i];

    if (tid < 16) {
        float s = 0.f, q = 0.f;
#pragma unroll
        for (int cc = 0; cc < 8; ++cc) {
            int idx = ((b * 16 + tid) * 8 + cc) * 2;
            s += partials[idx]; q += partials[idx + 1];
        }
        const float inv = 1.f / 262144.f;
        float mu = s * inv;
        float var = q * inv - mu * mu;
        mus[tid] = mu; rss[tid] = rsqrtf(var + 1e-5f);
    }
    __syncthreads();
    if (tid < 64) {
        float mu = mus[tid >> 2], rs = rss[tid >> 2];
        float sg = rs * gamma[tid];
        sch[tid] = make_float2(sg, beta[tid] - mu * sg);
    }
    __syncthreads();

    {
        float hi[8];
#pragma unroll
        for (int o2 = 0; o2 < 8; ++o2) hi[o2] = b_pre[o2];
        const float* fb = feat + ((size_t)b << 22) + P0 + tid;
#pragma unroll
        for (int ch = 0; ch < 64; ++ch) {
            float v = fb[(size_t)ch << 16];
            float2 ss = sch[ch];
            float pre = fmaxf(v * ss.x + ss.y, 0.f);
#pragma unroll
            for (int o2 = 0; o2 < 8; ++o2) hi[o2] += W_pre[o2 * 64 + ch] * pre;
        }
        float4 hq;
        hq.x = __builtin_bit_cast(float, __builtin_amdgcn_cvt_pkrtz(hi[0], hi[1]));
        hq.y = __builtin_bit_cast(float, __builtin_amdgcn_cvt_pkrtz(hi[2], hi[3]));
        hq.z = __builtin_bit_cast(float, __builtin_amdgcn_cvt_pkrtz(hi[4], hi[5]));
        hq.w = __builtin_bit_cast(float, __builtin_amdgcn_cvt_pkrtz(hi[6], hi[7]));
        hi_l[tid] = hq;
    }
    __syncthreads();

    const __fp16* ph = (const __fp16*)smem;
    int m = lane & 15;
    int kg = lane >> 4;
    int csel = m >> 3;
    int o = m & 7;
    int dup = kg & 1;
    int crow = kg >> 1;
    bool ok1 = (kg < 2);
    bool okBD = (crow == csel);
    bool act = (dup == 0);

    int cA = w << 2;
    int cB = cA + 2;
    Frags fa = make_frags(ph, smem, cA, csel, o, dup, crow, ok1, okBD);
    Frags fb2 = make_frags(ph, smem, cB, csel, o, dup, crow, ok1, okBD);

    float* ob = out + ((size_t)b << 21) + P0;
    float* cpA = ob + ((size_t)(cA + crow) << 16) + m;
    float* cpB = ob + ((size_t)(cB + crow) << 16) + m;
    const __fp16* hp = ph + 5120 + m * 8 + dup * 4;

#pragma unroll 4
    for (int g = 0; g < 32; ++g) {
        v4h B1 = *(const v4h*)(hp + g * 128);
        f32x4 d1a = __builtin_amdgcn_mfma_f32_16x16x16f16(fa.A1, B1, fa.C1, 0, 0, 0);
        f32x4 d1b = __builtin_amdgcn_mfma_f32_16x16x16f16(fb2.A1, B1, fb2.C1, 0, 0, 0);
        v4h p2a = relu_pack(d1a);
        v4h p2b = relu_pack(d1b);
        f32x4 d2a = __builtin_amdgcn_mfma_f32_16x16x16f16(fa.A2, p2a, fa.C2, 0, 0, 0);
        f32x4 d2b = __builtin_amdgcn_mfma_f32_16x16x16f16(fb2.A2, p2b, fb2.C2, 0, 0, 0);
        v4h p3a = relu_pack(d2a);
        v4h p3b = relu_pack(d2b);
        f32x4 d3a = __builtin_amdgcn_mfma_f32_16x16x16f16(fa.A3, p3a, fa.C3, 0, 0, 0);
        f32x4 d3b = __builtin_amdgcn_mfma_f32_16x16x16f16(fb2.A3, p3b, fb2.C3, 0, 0, 0);
        if (act) {
            cpA[g * 16] = d3a[0];
            cpB[g * 16] = d3b[0];
        }
    }
}

// ---------------- launch ----------------
extern "C" void kernel_launch(void* const* d_in, const int* in_sizes, int n_in,
                              void* d_out, int out_size, void* d_ws, size_t ws_size,
                              hipStream_t stream) {
    const float* dec4         = (const float*)d_in[0];
    const float* feat         = (const float*)d_in[1];
    const float* gn_pre_gamma = (const float*)d_in[2];
    const float* gn_pre_beta  = (const float*)d_in[3];
    const float* W_pre        = (const float*)d_in[4];
    const float* b_pre        = (const float*)d_in[5];
    const float* gn_gap_gamma = (const float*)d_in[6];
    const float* gn_gap_beta  = (const float*)d_in[7];
    const float* W_gap        = (const float*)d_in[8];
    const float* b_gap        = (const float*)d_in[9];
    const float* emb          = (const float*)d_in[10];
    const float* W_ctrl       = (const float*)d_in[11];
    const float* b_ctrl       = (const float*)d_in[12];
    float* out = (float*)d_out;
    float* ws  = (float*)d_ws;

    float* partials = ws;            // 1024 floats (512 x 2)
    float* g_buf    = ws + 1024;     // 2048
    float* E_ws     = ws + 3072;     // 4896
    unsigned char* pkB = (unsigned char*)(ws + 7968);  // 40960 B

    void* args[] = {
        (void*)&feat, (void*)&dec4, (void*)&gn_pre_gamma, (void*)&gn_pre_beta,
        (void*)&W_pre, (void*)&b_pre, (void*)&gn_gap_gamma, (void*)&gn_gap_beta,
        (void*)&W_gap, (void*)&b_gap, (void*)&emb, (void*)&W_ctrl, (void*)&b_ctrl,
        (void*)&out, (void*)&partials, (void*)&g_buf, (void*)&E_ws, (void*)&pkB
    };
    hipError_t err = hipLaunchCooperativeKernel((void*)mega, dim3(256), dim3(512),
                                                args, 0, stream);
    if (err != hipSuccess) {
        // Fallback: R13-exact 3-kernel path
        prep<<<608, 256, 0, stream>>>(feat, dec4, gn_gap_gamma, gn_gap_beta,
                                      emb, W_ctrl, partials, g_buf, E_ws);
        fc<<<4, 256, 0, stream>>>(g_buf, W_gap, b_gap, W_ctrl, b_ctrl, E_ws, pkB);
        mainK<<<512, 512, 0, stream>>>(feat, partials, gn_pre_gamma, gn_pre_beta,
                                       W_pre, b_pre, (const float4*)pkB, out);
    }
}

// Round 18
// 74.406 us; speedup vs baseline: 2.4580x; 2.4580x over previous
//
#include <hip/hip_runtime.h>
#include <hip/hip_fp16.h>

typedef __fp16 h2 __attribute__((ext_vector_type(2)));
typedef __fp16 v4h __attribute__((ext_vector_type(4)));
typedef float f32x4 __attribute__((ext_vector_type(4)));

__device__ inline float wave_sum(float v) {
#pragma unroll
    for (int off = 32; off > 0; off >>= 1) v += __shfl_down(v, off, 64);
    return v;
}

__device__ inline v4h relu_pack(f32x4 d) {
    h2 lo = __builtin_amdgcn_cvt_pkrtz(d[0], d[1]);
    h2 hi = __builtin_amdgcn_cvt_pkrtz(d[2], d[3]);
    h2 z = {(__fp16)0, (__fp16)0};
    lo = __builtin_elementwise_max(lo, z);
    hi = __builtin_elementwise_max(hi, z);
    v4h r = {lo.x, lo.y, hi.x, hi.y};
    return r;
}

// =============== Kernel 1: prep (608 blocks x 256) — R13 exact ===============
__global__ __launch_bounds__(256) void prep(
    const float* __restrict__ feat, const float* __restrict__ dec4,
    const float* __restrict__ gn_gap_gamma, const float* __restrict__ gn_gap_beta,
    const float* __restrict__ emb, const float* __restrict__ W_ctrl,
    float* __restrict__ partials, float* __restrict__ g_buf,
    float* __restrict__ E_ws) {
    int blk = blockIdx.x;
    int tid = threadIdx.x;
    int wid = tid >> 6, lane = tid & 63;
    if (blk < 512) {
        int grp = blk >> 3;     // b*16+g
        int chunk = blk & 7;
        const float4* base = (const float4*)(feat + (size_t)grp * 262144 + (size_t)chunk * 32768);
        float sa = 0.f, qa = 0.f, sb = 0.f, qb = 0.f;
#pragma unroll 8
        for (int i = 0; i < 16; ++i) {
            float4 v = base[i * 256 + tid];
            float4 u = base[(i + 16) * 256 + tid];
            sa += v.x + v.y + v.z + v.w;
            qa += v.x * v.x + v.y * v.y + v.z * v.z + v.w * v.w;
            sb += u.x + u.y + u.z + u.w;
            qb += u.x * u.x + u.y * u.y + u.z * u.z + u.w * u.w;
        }
        __shared__ float ls[4], lq[4];
        float s = wave_sum(sa + sb);
        float q = wave_sum(qa + qb);
        if (lane == 0) { ls[wid] = s; lq[wid] = q; }
        __syncthreads();
        if (tid == 0) {
            partials[blk * 2 + 0] = ls[0] + ls[1] + ls[2] + ls[3];
            partials[blk * 2 + 1] = lq[0] + lq[1] + lq[2] + lq[3];
        }
    } else if (blk < 576) {
        int idx = blk - 512;            // b*16+gi
        int b = idx >> 4, gi = idx & 15;
        const float* base = dec4 + (size_t)idx * 8192;
        int ch = tid >> 3, sub = tid & 7;
        const float4* r = (const float4*)(base + ch * 256 + sub * 32);
        float v[32];
        float s = 0.f, q = 0.f;
#pragma unroll
        for (int i = 0; i < 8; ++i) {
            float4 a = r[i];
            v[i * 4 + 0] = a.x; v[i * 4 + 1] = a.y; v[i * 4 + 2] = a.z; v[i * 4 + 3] = a.w;
            s += a.x + a.y + a.z + a.w;
            q += a.x * a.x + a.y * a.y + a.z * a.z + a.w * a.w;
        }
        __shared__ float ls[4], lq[4], bc[2];
        s = wave_sum(s); q = wave_sum(q);
        if (lane == 0) { ls[wid] = s; lq[wid] = q; }
        __syncthreads();
        if (tid == 0) {
            float S = ls[0] + ls[1] + ls[2] + ls[3];
            float Q = lq[0] + lq[1] + lq[2] + lq[3];
            const float inv = 1.f / 8192.f;
            float mu = S * inv;
            float var = Q * inv - mu * mu;
            bc[0] = mu;
            bc[1] = rsqrtf(var + 1e-5f);
        }
        __syncthreads();
        float mu = bc[0], rs = bc[1];
        int c = gi * 32 + ch;
        float sc = rs * gn_gap_gamma[c];
        float sh = gn_gap_beta[c] - mu * sc;
        float acc = 0.f;
#pragma unroll
        for (int i = 0; i < 32; ++i) acc += fmaxf(v[i] * sc + sh, 0.f);
#pragma unroll
        for (int m = 1; m < 8; m <<= 1) acc += __shfl_xor(acc, m, 64);
        if (sub == 0) g_buf[b * 512 + c] = acc * (1.f / 256.f);
    } else {
        int c = blk - 576;
        __shared__ float es[256];
        es[tid] = emb[c * 256 + tid];
        __syncthreads();
        if (tid < 153) {
            const float4* w4 = (const float4*)(W_ctrl + tid * 512 + 256);
            const float4* e4 = (const float4*)es;
            float acc = 0.f;
#pragma unroll 8
            for (int k = 0; k < 64; ++k) {
                float4 a = w4[k], e = e4[k];
                acc += a.x * e.x + a.y * e.y + a.z * e.z + a.w * e.w;
            }
            E_ws[c * 153 + tid] = acc;
        }
    }
}

// =============== Kernel 2: fc (4 blocks x 256) — R13 exact ===============
__global__ __launch_bounds__(256) void fc(
    const float* __restrict__ g_buf, const float* __restrict__ W_gap,
    const float* __restrict__ b_gap, const float* __restrict__ W_ctrl,
    const float* __restrict__ b_ctrl, const float* __restrict__ E_ws,
    unsigned char* __restrict__ pk) {
    int b = blockIdx.x, tid = threadIdx.x;
    __shared__ float gs[512];
    __shared__ float xf[256];
    __shared__ float F[160];
    gs[tid] = g_buf[b * 512 + tid];
    gs[tid + 256] = g_buf[b * 512 + 256 + tid];
    __syncthreads();
    {
        const float4* w = (const float4*)(W_gap + tid * 512);
        const float4* g4 = (const float4*)gs;
        float acc = b_gap[tid];
#pragma unroll 8
        for (int k = 0; k < 128; ++k) {
            float4 wv = w[k], gv = g4[k];
            acc += wv.x * gv.x + wv.y * gv.y + wv.z * gv.z + wv.w * gv.w;
        }
        xf[tid] = acc;
    }
    __syncthreads();
    if (tid < 160) {
        float acc = 0.f;
        if (tid < 153) {
            const float4* w = (const float4*)(W_ctrl + tid * 512);
            const float4* x4 = (const float4*)xf;
#pragma unroll 8
            for (int k = 0; k < 64; ++k) {
                float4 wv = w[k], xv = x4[k];
                acc += wv.x * xv.x + wv.y * xv.y + wv.z * xv.z + wv.w * xv.w;
            }
            acc += b_ctrl[tid];
        }
        F[tid] = acc;
    }
    __syncthreads();
    unsigned char* dst = pk + (size_t)b * 10240;
    for (int c = 0; c < 32; ++c) {
        if (tid < 152) {
            float v = F[tid] + E_ws[c * 153 + tid];
            ((__fp16*)(dst + c * 320))[tid] = (__fp16)v;
        } else if (tid == 152) {
            *(float*)(dst + c * 320 + 304) = F[152] + E_ws[c * 153 + 152];
        }
    }
}

// ---- per-c-pair MFMA fragments (R13-verified mapping) ----
struct Frags { v4h A1, A2, A3; f32x4 C1, C2, C3; };

__device__ inline Frags make_frags(const __fp16* ph, const float* smemf, int c0,
                                   int csel, int o, int dup, int crow,
                                   bool ok1, bool okBD) {
    Frags f;
    int cbA = (c0 + csel) * 160;
    int cbB = (c0 + crow) * 160;
    v4h z = {(__fp16)0, (__fp16)0, (__fp16)0, (__fp16)0};
    v4h a1 = *(const v4h*)(ph + cbA + o * 8 + dup * 4);
    v4h a2 = *(const v4h*)(ph + cbA + 64 + o * 8 + dup * 4);
    v4h a3 = *(const v4h*)(ph + cbA + 128 + dup * 4);
    f.A1 = ok1 ? a1 : z;
    f.A2 = okBD ? a2 : z;
    f.A3 = (okBD && o == 0) ? a3 : z;
    v4h b1 = *(const v4h*)(ph + cbB + 136 + dup * 4);
    v4h b2 = *(const v4h*)(ph + cbB + 144 + dup * 4);
    f.C1 = f32x4{(float)b1.x, (float)b1.y, (float)b1.z, (float)b1.w};
    f.C2 = f32x4{(float)b2.x, (float)b2.y, (float)b2.z, (float)b2.w};
    f.C3 = f32x4{0.f, 0.f, 0.f, 0.f};
    if (dup == 0) f.C3[0] = smemf[(c0 + crow) * 80 + 76];
    return f;
}

// =============== Kernel 3: mainK (512 blocks x 512, 8 waves) — R13 exact ===============
__global__ __launch_bounds__(512, 4) void mainK(
    const float* __restrict__ feat, const float* __restrict__ partials,
    const float* __restrict__ gamma, const float* __restrict__ beta,
    const float* __restrict__ W_pre, const float* __restrict__ b_pre,
    const float4* __restrict__ pk, float* __restrict__ out) {
    int blk = blockIdx.x;            // 0..511
    int b = blk >> 7;
    int tid = threadIdx.x;
    int w = tid >> 6, lane = tid & 63;
    int P0 = (blk & 127) << 9;       // 512-px tile

    __shared__ __align__(16) float smem[4768];  // 19072 B
    float4* pp   = (float4*)smem;               // [0,2560) packed params
    float4* hi_l = (float4*)(smem + 2560);      // [2560,4608) hi_l[px] f16x8
    float2* sch  = (float2*)(smem + 4608);      // 64 x (scale, shift)
    float* mus = smem + 4736;                   // 16
    float* rss = smem + 4752;                   // 16

    const float4* src = pk + (size_t)b * 640;
    for (int i = tid; i < 640; i += 512) pp[i] = src[i];

    if (tid < 16) {
        float s = 0.f, q = 0.f;
#pragma unroll
        for (int cc = 0; cc < 8; ++cc) {
            int idx = ((b * 16 + tid) * 8 + cc) * 2;
            s += partials[idx]; q += partials[idx + 1];
        }
        const float inv = 1.f / 262144.f;
        float mu = s * inv;
        float var = q * inv - mu * mu;
        mus[tid] = mu; rss[tid] = rsqrtf(var + 1e-5f);
    }
    __syncthreads();
    if (tid < 64) {
        float mu = mus[tid >> 2], rs = rss[tid >> 2];
        float sg = rs * gamma[tid];
        sch[tid] = make_float2(sg, beta[tid] - mu * sg);
    }
    __syncthreads();

    // head: 1 px per thread -> hi_l[tid]
    {
        float hi[8];
#pragma unroll
        for (int o2 = 0; o2 < 8; ++o2) hi[o2] = b_pre[o2];
        const float* fb = feat + ((size_t)b << 22) + P0 + tid;
#pragma unroll
        for (int ch = 0; ch < 64; ++ch) {
            float v = fb[(size_t)ch << 16];
            float2 ss = sch[ch];
            float pre = fmaxf(v * ss.x + ss.y, 0.f);
#pragma unroll
            for (int o2 = 0; o2 < 8; ++o2) hi[o2] += W_pre[o2 * 64 + ch] * pre;
        }
        float4 hq;
        hq.x = __builtin_bit_cast(float, __builtin_amdgcn_cvt_pkrtz(hi[0], hi[1]));
        hq.y = __builtin_bit_cast(float, __builtin_amdgcn_cvt_pkrtz(hi[2], hi[3]));
        hq.z = __builtin_bit_cast(float, __builtin_amdgcn_cvt_pkrtz(hi[4], hi[5]));
        hq.w = __builtin_bit_cast(float, __builtin_amdgcn_cvt_pkrtz(hi[6], hi[7]));
        hi_l[tid] = hq;
    }
    __syncthreads();

    // ---- MFMA MLP ----
    const __fp16* ph = (const __fp16*)smem;
    int m = lane & 15;
    int kg = lane >> 4;
    int csel = m >> 3;
    int o = m & 7;
    int dup = kg & 1;
    int crow = kg >> 1;
    bool ok1 = (kg < 2);
    bool okBD = (crow == csel);
    bool act = (dup == 0);

    int cA = w << 2;
    int cB = cA + 2;
    Frags fa = make_frags(ph, smem, cA, csel, o, dup, crow, ok1, okBD);
    Frags fb2 = make_frags(ph, smem, cB, csel, o, dup, crow, ok1, okBD);

    float* ob = out + ((size_t)b << 21) + P0;
    float* cpA = ob + ((size_t)(cA + crow) << 16) + m;
    float* cpB = ob + ((size_t)(cB + crow) << 16) + m;
    const __fp16* hp = ph + 5120 + m * 8 + dup * 4;

#pragma unroll 4
    for (int g = 0; g < 32; ++g) {
        v4h B1 = *(const v4h*)(hp + g * 128);
        f32x4 d1a = __builtin_amdgcn_mfma_f32_16x16x16f16(fa.A1, B1, fa.C1, 0, 0, 0);
        f32x4 d1b = __builtin_amdgcn_mfma_f32_16x16x16f16(fb2.A1, B1, fb2.C1, 0, 0, 0);
        v4h p2a = relu_pack(d1a);
        v4h p2b = relu_pack(d1b);
        f32x4 d2a = __builtin_amdgcn_mfma_f32_16x16x16f16(fa.A2, p2a, fa.C2, 0, 0, 0);
        f32x4 d2b = __builtin_amdgcn_mfma_f32_16x16x16f16(fb2.A2, p2b, fb2.C2, 0, 0, 0);
        v4h p3a = relu_pack(d2a);
        v4h p3b = relu_pack(d2b);
        f32x4 d3a = __builtin_amdgcn_mfma_f32_16x16x16f16(fa.A3, p3a, fa.C3, 0, 0, 0);
        f32x4 d3b = __builtin_amdgcn_mfma_f32_16x16x16f16(fb2.A3, p3b, fb2.C3, 0, 0, 0);
        if (act) {
            cpA[g * 16] = d3a[0];
            cpB[g * 16] = d3b[0];
        }
    }
}

// ---------------- launch ----------------
extern "C" void kernel_launch(void* const* d_in, const int* in_sizes, int n_in,
                              void* d_out, int out_size, void* d_ws, size_t ws_size,
                              hipStream_t stream) {
    const float* dec4         = (const float*)d_in[0];
    const float* feat         = (const float*)d_in[1];
    const float* gn_pre_gamma = (const float*)d_in[2];
    const float* gn_pre_beta  = (const float*)d_in[3];
    const float* W_pre        = (const float*)d_in[4];
    const float* b_pre        = (const float*)d_in[5];
    const float* gn_gap_gamma = (const float*)d_in[6];
    const float* gn_gap_beta  = (const float*)d_in[7];
    const float* W_gap        = (const float*)d_in[8];
    const float* b_gap        = (const float*)d_in[9];
    const float* emb          = (const float*)d_in[10];
    const float* W_ctrl       = (const float*)d_in[11];
    const float* b_ctrl       = (const float*)d_in[12];
    float* out = (float*)d_out;
    float* ws  = (float*)d_ws;

    float* partials = ws;            // 1024 floats (512 x 2)
    float* g_buf    = ws + 1024;     // 2048
    float* E_ws     = ws + 3072;     // 4896
    unsigned char* pkB = (unsigned char*)(ws + 7968);  // 40960 B (16B-aligned)

    prep<<<608, 256, 0, stream>>>(feat, dec4, gn_gap_gamma, gn_gap_beta,
                                  emb, W_ctrl, partials, g_buf, E_ws);
    fc<<<4, 256, 0, stream>>>(g_buf, W_gap, b_gap, W_ctrl, b_ctrl, E_ws, pkB);
    mainK<<<512, 512, 0, stream>>>(feat, partials, gn_pre_gamma, gn_pre_beta,
                                   W_pre, b_pre, (const float4*)pkB, out);
}